// Round 15
// baseline (2565.923 us; speedup 1.0000x reference)
//
#include <hip/hip_runtime.h>
#include <hip/hip_bf16.h>
#include <stdint.h>

// Problem constants (QuantizedLinear_15985868276124)
#define IN_F   4096                 // bytes per i8 row == elements
#define OUT_F  11008
#define M_TOK  8192

typedef __attribute__((ext_vector_type(4))) int   int32x4;

// ---------- block row-max reduction helper ----------
__device__ __forceinline__ float block_rowmax(float m, float* red, int t) {
    red[t] = m; __syncthreads();
    for (int s = 128; s > 0; s >>= 1) {
        if (t < s) red[t] = fmaxf(red[t], red[t + s]);
        __syncthreads();
    }
    float r = red[0]; __syncthreads();
    return fmaxf(r, 1e-8f);
}

// ---------- kernel 1: quantize x rows -> i8 + sx ----------
__global__ __launch_bounds__(256) void k_qx(
        const float* __restrict__ x, signed char* __restrict__ Xq,
        float* __restrict__ sx) {
    __shared__ float red[256];
    int r = blockIdx.x, t = threadIdx.x;
    const float4* xr = (const float4*)(x + (size_t)r * IN_F) + t * 4;
    float4 v0 = xr[0], v1 = xr[1], v2 = xr[2], v3 = xr[3];
    float m = 0.f;
#define MX4(v) m = fmaxf(m, fmaxf(fmaxf(fabsf(v.x), fabsf(v.y)), fmaxf(fabsf(v.z), fabsf(v.w))))
    MX4(v0); MX4(v1); MX4(v2); MX4(v3);
    float rm = block_rowmax(m, red, t);
    if (t == 0) sx[r] = rm / 127.f;
    float inv = 127.f / rm;
    union { signed char c[16]; uint4 u; } pk;
#define Q4(v, o) pk.c[o] = (signed char)__float2int_rn(v.x * inv);            \
                 pk.c[o+1] = (signed char)__float2int_rn(v.y * inv);          \
                 pk.c[o+2] = (signed char)__float2int_rn(v.z * inv);          \
                 pk.c[o+3] = (signed char)__float2int_rn(v.w * inv)
    Q4(v0, 0); Q4(v1, 4); Q4(v2, 8); Q4(v3, 12);
    *(uint4*)(Xq + (size_t)r * IN_F + t * 16) = pk.u;
}

// ---------- kernel 2: dequant + quantize W rows -> i8 + sw ----------
__global__ __launch_bounds__(256) void k_qw(
        const int* __restrict__ codes,
        const float* __restrict__ codebooks,
        const float* __restrict__ scales,
        signed char* __restrict__ Wq, float* __restrict__ sw) {
    __shared__ float cb[4096];  // [2][256][8]
    __shared__ float red[256];
    int o = blockIdx.x, t = threadIdx.x;
    {
        const float4* cbg = (const float4*)codebooks;
        float4* cbl = (float4*)cb;
#pragma unroll
        for (int i = 0; i < 4; ++i) cbl[t + i * 256] = cbg[t + i * 256];
    }
    __syncthreads();
    const int2* cp = (const int2*)codes + (size_t)o * 512 + t * 2;
    int2 c0 = cp[0], c1 = cp[1];
    float e[16]; float m = 0.f;
#pragma unroll
    for (int j = 0; j < 8; ++j) {
        e[j]     = cb[c0.x * 8 + j] + cb[2048 + c0.y * 8 + j];
        e[8 + j] = cb[c1.x * 8 + j] + cb[2048 + c1.y * 8 + j];
    }
#pragma unroll
    for (int j = 0; j < 16; ++j) m = fmaxf(m, fabsf(e[j]));
    float rm = block_rowmax(m, red, t);
    if (t == 0) sw[o] = scales[o] * rm / 127.f;
    float inv = 127.f / rm;
    union { signed char c[16]; uint4 u; } pk;
#pragma unroll
    for (int j = 0; j < 16; ++j) pk.c[j] = (signed char)__float2int_rn(e[j] * inv);
    *(uint4*)(Wq + (size_t)o * IN_F + t * 16) = pk.u;
}

// ---------- kernel 3: 256x256 i8 GEMM, SINGLE-buffer LDS, 2 blocks/CU ------
// R15: LDS 64 KiB (no double buffer) -> 2 blocks/CU. The per-K-tile VMW(0)
// drain is now covered by the co-resident block's MFMA work (m114-style
// TLP overlap), instead of explicit pipelining. WAR-safe: phases A/B/C
// consume all of tile t into regs (each phase's ds_reads drained by its own
// QUAD before the phase barrier), so D may overwrite the buffer.

#define BARRIER() __builtin_amdgcn_s_barrier()
#define VMW(n)    asm volatile("s_waitcnt vmcnt(" #n ")")

#define GL16(gp, lp) __builtin_amdgcn_global_load_lds(                        \
    (const __attribute__((address_space(1))) void*)(gp),                      \
    (__attribute__((address_space(3))) void*)(lp), 16, 0, 0)

__global__ __launch_bounds__(512, 4) void k_gemm(
        const signed char* __restrict__ A,   // [M_TOK][IN_F] i8
        const signed char* __restrict__ B,   // [OUT_F][IN_F] i8 (B^T layout)
        const float* __restrict__ sx,        // [M_TOK]
        const float* __restrict__ sw,        // [OUT_F]
        const float* __restrict__ bias,
        float* __restrict__ out) {
    __shared__ signed char lA[256 * 128];   // 32 KiB
    __shared__ signed char lB[256 * 128];   // 32 KiB

    const int tid = threadIdx.x;
    const int l = tid & 63;
    const int w = tid >> 6;            // wave 0..7
    const int wm = w >> 2, wn = w & 3; // 2 x 4 wave grid; wave tile 128x64

    // T1: bijective XCD swizzle. grid 1376 = 8 XCD * (4 row-chunks * 43 cols)
    int lid = blockIdx.x;
    int xcd = lid & 7, j = lid >> 3;
    int bx = j >> 2;                   // col block 0..42
    int by = (xcd << 2) + (j & 3);     // row block 0..31
    const int rowBase = by * 256;
    const int colBase = bx * 256;

    // ---- staging addressing (swizzle on GLOBAL source; LDS linear)
    const int srow = w * 8 + (l >> 3);
    const int scol = ((l & 7) ^ ((l >> 3) & 7)) << 4;   // byte offset in row
    const signed char* gA = A + (size_t)(rowBase + srow) * IN_F + scol;
    const signed char* gB = B + (size_t)(colBase + srow) * IN_F + scol;
    signed char* lAw = &lA[w * 8 * 128];
    signed char* lBw = &lB[w * 8 * 128];

    // stage full K-tile t (128 bytes of K): 8 GL16 per wave
#define STAGE8(t) do {                                                        \
    const signed char* _ga = gA + (size_t)(t) * 128;                          \
    const signed char* _gb = gB + (size_t)(t) * 128;                          \
    GL16(_ga,                      lAw);                                      \
    GL16(_ga +  64 * IN_F,         lAw +  64 * 128);                          \
    GL16(_ga + 128 * IN_F,         lAw + 128 * 128);                          \
    GL16(_ga + 192 * IN_F,         lAw + 192 * 128);                          \
    GL16(_gb,                      lBw);                                      \
    GL16(_gb +  64 * IN_F,         lBw +  64 * 128);                          \
    GL16(_gb + 128 * IN_F,         lBw + 128 * 128);                          \
    GL16(_gb + 192 * IN_F,         lBw + 192 * 128);                          \
} while (0)

    // ---- fragment reads: lane row = frag*16 + (l&15); 16B at chunk
    // (kk*4 + (l>>4)) ^ (row&7)
    const int frow = l & 15, g = l >> 4;
    const int cho0 = ((g ^ (frow & 7)) << 4);
    const int cho1 = (((4 + g) ^ (frow & 7)) << 4);
    const char* rowA = (const char*)&lA[(wm * 128 + frow) * 128];
    const char* rowB = (const char*)&lB[(wn * 64 + frow) * 128];
#define LDA_(m, kk) (*(const int32x4*)(rowA + (m) * 2048 + ((kk) ? cho1 : cho0)))
#define LDB_(n, kk) (*(const int32x4*)(rowB + (n) * 2048 + ((kk) ? cho1 : cho0)))

    int32x4 acc[8][4] = {};
    int32x4 ar[4][2], br[4][2];

#define QUAD(M0, N0) do {                                                     \
    __builtin_amdgcn_s_setprio(1);                                            \
    _Pragma("unroll") for (int mm = 0; mm < 4; ++mm)                          \
    _Pragma("unroll") for (int nn = 0; nn < 2; ++nn)                          \
    _Pragma("unroll") for (int kk = 0; kk < 2; ++kk)                          \
        acc[(M0) + mm][(N0) + nn] = __builtin_amdgcn_mfma_i32_16x16x64_i8(    \
            ar[mm][kk], br[(N0) + nn][kk], acc[(M0) + mm][(N0) + nn], 0, 0, 0);\
    __builtin_amdgcn_s_setprio(0);                                            \
} while (0)

#define RD_A03_B01() do {                                                     \
    _Pragma("unroll") for (int mm = 0; mm < 4; ++mm) {                        \
        ar[mm][0] = LDA_(mm, 0); ar[mm][1] = LDA_(mm, 1); }                   \
    br[0][0] = LDB_(0, 0); br[0][1] = LDB_(0, 1);                             \
    br[1][0] = LDB_(1, 0); br[1][1] = LDB_(1, 1);                             \
} while (0)
#define RD_B23() do {                                                         \
    br[2][0] = LDB_(2, 0); br[2][1] = LDB_(2, 1);                             \
    br[3][0] = LDB_(3, 0); br[3][1] = LDB_(3, 1);                             \
} while (0)
#define RD_A47() do {                                                         \
    _Pragma("unroll") for (int mm = 0; mm < 4; ++mm) {                        \
        ar[mm][0] = LDA_(4 + mm, 0); ar[mm][1] = LDA_(4 + mm, 1); }           \
} while (0)

    // prologue: stage tile0; publish
    STAGE8(0);
    VMW(0); BARRIER();

    // main loop: 32 K-tiles; phases A/B/C read tile t, D stages t+1
    for (int t = 0; t < 32; ++t) {
        // A
        RD_A03_B01();
        QUAD(0, 0); BARRIER();
        // B
        RD_B23();
        QUAD(0, 2); BARRIER();
        // C: last reads of tile t (all reads complete at this barrier)
        RD_A47();
        QUAD(4, 2); BARRIER();
        // D: overwrite buffer with t+1; MFMA overlaps load flight; publish
        if (t < 31) STAGE8(t + 1);
        QUAD(4, 0);
        VMW(0); BARRIER();
    }

    // epilogue: C/D layout col = lane&15, row = (lane>>4)*4 + jj
    // out = sx[row]*sw[col]*acc + bias[col]
#pragma unroll
    for (int n = 0; n < 4; ++n) {
        int gcol = colBase + wn * 64 + n * 16 + frow;
        float swv = sw[gcol];
        float bv = bias[gcol];
#pragma unroll
        for (int m = 0; m < 8; ++m) {
            int grow0 = rowBase + wm * 128 + m * 16 + g * 4;
            float4 sx4 = *(const float4*)&sx[grow0];
            out[(size_t)(grow0 + 0) * OUT_F + gcol] = (float)acc[m][n][0] * sx4.x * swv + bv;
            out[(size_t)(grow0 + 1) * OUT_F + gcol] = (float)acc[m][n][1] * sx4.y * swv + bv;
            out[(size_t)(grow0 + 2) * OUT_F + gcol] = (float)acc[m][n][2] * sx4.z * swv + bv;
            out[(size_t)(grow0 + 3) * OUT_F + gcol] = (float)acc[m][n][3] * sx4.w * swv + bv;
        }
    }
}

// ---------- launch ----------
extern "C" void kernel_launch(void* const* d_in, const int* in_sizes, int n_in,
                              void* d_out, int out_size, void* d_ws, size_t ws_size,
                              hipStream_t stream) {
    const float* x         = (const float*)d_in[0];
    const int*   codes     = (const int*)d_in[1];
    const float* codebooks = (const float*)d_in[2];
    const float* scales    = (const float*)d_in[3];
    const float* bias      = (const float*)d_in[4];
    float* out = (float*)d_out;

    // workspace: Wq i8 [OUT_F][IN_F]; Xq i8 [M_TOK][IN_F]; sx; sw (~78.7 MB)
    signed char* Wq = (signed char*)d_ws;
    signed char* Xq = Wq + (size_t)OUT_F * IN_F;
    float* sx = (float*)(Xq + (size_t)M_TOK * IN_F);
    float* sw = sx + M_TOK;

    k_qx<<<M_TOK, 256, 0, stream>>>(x, Xq, sx);
    k_qw<<<OUT_F, 256, 0, stream>>>(codes, codebooks, scales, Wq, sw);
    // grid: (8192/256) * (11008/256) = 32 * 43 = 1376 blocks, 512 threads
    k_gemm<<<1376, 512, 0, stream>>>(Xq, Wq, sx, sw, bias, out);
}

// Round 16
// 470.840 us; speedup vs baseline: 5.4497x; 5.4497x over previous
//
#include <hip/hip_runtime.h>
#include <hip/hip_bf16.h>
#include <stdint.h>

// Problem constants (QuantizedLinear_15985868276124)
#define IN_F   4096                 // bytes per i8 row == elements
#define OUT_F  11008
#define M_TOK  8192

typedef __attribute__((ext_vector_type(4))) int   int32x4;

// ---------- block row-max reduction helper ----------
__device__ __forceinline__ float block_rowmax(float m, float* red, int t) {
    red[t] = m; __syncthreads();
    for (int s = 128; s > 0; s >>= 1) {
        if (t < s) red[t] = fmaxf(red[t], red[t + s]);
        __syncthreads();
    }
    float r = red[0]; __syncthreads();
    return fmaxf(r, 1e-8f);
}

// ---------- kernel 1: quantize x rows -> i8 + sx ----------
__global__ __launch_bounds__(256) void k_qx(
        const float* __restrict__ x, signed char* __restrict__ Xq,
        float* __restrict__ sx) {
    __shared__ float red[256];
    int r = blockIdx.x, t = threadIdx.x;
    const float4* xr = (const float4*)(x + (size_t)r * IN_F) + t * 4;
    float4 v0 = xr[0], v1 = xr[1], v2 = xr[2], v3 = xr[3];
    float m = 0.f;
#define MX4(v) m = fmaxf(m, fmaxf(fmaxf(fabsf(v.x), fabsf(v.y)), fmaxf(fabsf(v.z), fabsf(v.w))))
    MX4(v0); MX4(v1); MX4(v2); MX4(v3);
    float rm = block_rowmax(m, red, t);
    if (t == 0) sx[r] = rm / 127.f;
    float inv = 127.f / rm;
    union { signed char c[16]; uint4 u; } pk;
#define Q4(v, o) pk.c[o] = (signed char)__float2int_rn(v.x * inv);            \
                 pk.c[o+1] = (signed char)__float2int_rn(v.y * inv);          \
                 pk.c[o+2] = (signed char)__float2int_rn(v.z * inv);          \
                 pk.c[o+3] = (signed char)__float2int_rn(v.w * inv)
    Q4(v0, 0); Q4(v1, 4); Q4(v2, 8); Q4(v3, 12);
    *(uint4*)(Xq + (size_t)r * IN_F + t * 16) = pk.u;
}

// ---------- kernel 2: dequant + quantize W rows -> i8 + sw ----------
__global__ __launch_bounds__(256) void k_qw(
        const int* __restrict__ codes,
        const float* __restrict__ codebooks,
        const float* __restrict__ scales,
        signed char* __restrict__ Wq, float* __restrict__ sw) {
    __shared__ float cb[4096];  // [2][256][8]
    __shared__ float red[256];
    int o = blockIdx.x, t = threadIdx.x;
    {
        const float4* cbg = (const float4*)codebooks;
        float4* cbl = (float4*)cb;
#pragma unroll
        for (int i = 0; i < 4; ++i) cbl[t + i * 256] = cbg[t + i * 256];
    }
    __syncthreads();
    const int2* cp = (const int2*)codes + (size_t)o * 512 + t * 2;
    int2 c0 = cp[0], c1 = cp[1];
    float e[16]; float m = 0.f;
#pragma unroll
    for (int j = 0; j < 8; ++j) {
        e[j]     = cb[c0.x * 8 + j] + cb[2048 + c0.y * 8 + j];
        e[8 + j] = cb[c1.x * 8 + j] + cb[2048 + c1.y * 8 + j];
    }
#pragma unroll
    for (int j = 0; j < 16; ++j) m = fmaxf(m, fabsf(e[j]));
    float rm = block_rowmax(m, red, t);
    if (t == 0) sw[o] = scales[o] * rm / 127.f;
    float inv = 127.f / rm;
    union { signed char c[16]; uint4 u; } pk;
#pragma unroll
    for (int j = 0; j < 16; ++j) pk.c[j] = (signed char)__float2int_rn(e[j] * inv);
    *(uint4*)(Wq + (size_t)o * IN_F + t * 16) = pk.u;
}

// ---------- kernel 3: 256x256 i8 GEMM, 2 regions / K-tile ----------
// R16 = R14 (dbuf, 4 static LDS buffers, 1 block/CU) with phases merged:
// 2 barriers per K-tile (was 4). Bigger barrier-free regions let waves skew
// so one wave's MFMA covers another's ds_reads (LDS 2304 vs MFMA 2611
// cyc/K-tile currently serialize to ~5580).
// Staging protocol (tile n >= 2): B-half @ R2(n-2), A-half @ R1(n-1);
// VMW(4) @ R2(n-1) retires n (12 outstanding -> 4); barrier publishes; read
// @ R1(n). All stages land after the barrier draining their buffer's prior
// reads (per-site WAR check in comments below).
// NOTE R15 lesson: this tile NEEDS ~250 regs/thread (acc=128 in AGPR).
// launch_bounds(512,2) — (512,4) forces a 128-reg cap -> acc spills -> 6x.

#define BARRIER() __builtin_amdgcn_s_barrier()
#define VMW(n)    asm volatile("s_waitcnt vmcnt(" #n ")")

#define GL16(gp, lp) __builtin_amdgcn_global_load_lds(                        \
    (const __attribute__((address_space(1))) void*)(gp),                      \
    (__attribute__((address_space(3))) void*)(lp), 16, 0, 0)

__global__ __launch_bounds__(512, 2) void k_gemm(
        const signed char* __restrict__ A,   // [M_TOK][IN_F] i8
        const signed char* __restrict__ B,   // [OUT_F][IN_F] i8 (B^T layout)
        const float* __restrict__ sx,        // [M_TOK]
        const float* __restrict__ sw,        // [OUT_F]
        const float* __restrict__ bias,
        float* __restrict__ out) {
    __shared__ signed char lA0[256 * 128];   // 32 KiB each
    __shared__ signed char lA1[256 * 128];
    __shared__ signed char lB0[256 * 128];
    __shared__ signed char lB1[256 * 128];

    const int tid = threadIdx.x;
    const int l = tid & 63;
    const int w = tid >> 6;            // wave 0..7
    const int wm = w >> 2, wn = w & 3; // 2 x 4 wave grid; wave tile 128x64

    // T1: bijective XCD swizzle. grid 1376 = 8 XCD * (4 row-chunks * 43 cols)
    int lid = blockIdx.x;
    int xcd = lid & 7, j = lid >> 3;
    int bx = j >> 2;                   // col block 0..42
    int by = (xcd << 2) + (j & 3);     // row block 0..31
    const int rowBase = by * 256;
    const int colBase = bx * 256;

    // ---- staging addressing (swizzle on GLOBAL source; LDS linear)
    const int srow = w * 8 + (l >> 3);
    const int scol = ((l & 7) ^ ((l >> 3) & 7)) << 4;   // byte offset in row
    const signed char* gA = A + (size_t)(rowBase + srow) * IN_F + scol;
    const signed char* gB = B + (size_t)(colBase + srow) * IN_F + scol;
    signed char* lA0w = &lA0[w * 8 * 128];
    signed char* lA1w = &lA1[w * 8 * 128];
    signed char* lB0w = &lB0[w * 8 * 128];
    signed char* lB1w = &lB1[w * 8 * 128];

    // stage one quarter of K-tile t into buffer P: q0/q1 = A rows
    // {0-127,128-255}; q2/q3 = B same
#define STAGEQ_(P, t, q) do {                                                 \
    const signed char* _g = (((q) < 2) ? gA : gB) + (size_t)(t) * 128;        \
    signed char* _l = (((q) < 2) ? lA##P##w : lB##P##w);                      \
    const int _r = ((q) & 1) * 128;                                           \
    GL16(_g + (size_t)_r * IN_F,        _l + _r * 128);                       \
    GL16(_g + (size_t)(_r + 64) * IN_F, _l + (_r + 64) * 128);                \
} while (0)

    // ---- fragment reads: lane row = frag*16 + (l&15); 16B at chunk
    // (kk*4 + (l>>4)) ^ (row&7)
    const int frow = l & 15, g = l >> 4;
    const int cho0 = ((g ^ (frow & 7)) << 4);
    const int cho1 = (((4 + g) ^ (frow & 7)) << 4);
    const char* rowA0 = (const char*)&lA0[(wm * 128 + frow) * 128];
    const char* rowA1 = (const char*)&lA1[(wm * 128 + frow) * 128];
    const char* rowB0 = (const char*)&lB0[(wn * 64 + frow) * 128];
    const char* rowB1 = (const char*)&lB1[(wn * 64 + frow) * 128];
#define LDA_(P, m, kk) (*(const int32x4*)(rowA##P + (m) * 2048 + ((kk) ? cho1 : cho0)))
#define LDB_(P, n, kk) (*(const int32x4*)(rowB##P + (n) * 2048 + ((kk) ? cho1 : cho0)))

    int32x4 acc[8][4] = {};
    int32x4 ar[4][2], br[4][2];

#define QUAD(M0, N0) do {                                                     \
    __builtin_amdgcn_s_setprio(1);                                            \
    _Pragma("unroll") for (int mm = 0; mm < 4; ++mm)                          \
    _Pragma("unroll") for (int nn = 0; nn < 2; ++nn)                          \
    _Pragma("unroll") for (int kk = 0; kk < 2; ++kk)                          \
        acc[(M0) + mm][(N0) + nn] = __builtin_amdgcn_mfma_i32_16x16x64_i8(    \
            ar[mm][kk], br[(N0) + nn][kk], acc[(M0) + mm][(N0) + nn], 0, 0, 0);\
    __builtin_amdgcn_s_setprio(0);                                            \
} while (0)

#define RD_A03_B01(P) do {                                                    \
    _Pragma("unroll") for (int mm = 0; mm < 4; ++mm) {                        \
        ar[mm][0] = LDA_(P, mm, 0); ar[mm][1] = LDA_(P, mm, 1); }             \
    br[0][0] = LDB_(P, 0, 0); br[0][1] = LDB_(P, 0, 1);                       \
    br[1][0] = LDB_(P, 1, 0); br[1][1] = LDB_(P, 1, 1);                       \
} while (0)
#define RD_B23(P) do {                                                        \
    br[2][0] = LDB_(P, 2, 0); br[2][1] = LDB_(P, 2, 1);                       \
    br[3][0] = LDB_(P, 3, 0); br[3][1] = LDB_(P, 3, 1);                       \
} while (0)
#define RD_A47(P) do {                                                        \
    _Pragma("unroll") for (int mm = 0; mm < 4; ++mm) {                        \
        ar[mm][0] = LDA_(P, 4 + mm, 0); ar[mm][1] = LDA_(P, 4 + mm, 1); }     \
} while (0)

    // prologue: stage t0 full (buf0) + t1 B-half (buf1); VMW(4) retires t0
    STAGEQ_(0, 0, 0); STAGEQ_(0, 0, 1); STAGEQ_(0, 0, 2); STAGEQ_(0, 0, 3);
    STAGEQ_(1, 1, 2); STAGEQ_(1, 1, 3);
    VMW(4); BARRIER();

    // main loop: 2 K-tiles/iter (e=2i buf0, o=2i+1 buf1); i = 0..14 (tiles 0..29)
    for (int i = 0; i < 15; ++i) {
        int e = 2 * i, o = 2 * i + 1;
        // R1(e): stage A-half(o)->lA1 [WAR: tile o-2's ar reads ended at
        // R4(prev)'s barrier]; reads buf0 ar03,br01 -> QUAD(0,0); br23 -> QUAD(0,2)
        RD_A03_B01(0);
        STAGEQ_(1, o, 0); STAGEQ_(1, o, 1);
        QUAD(0, 0);
        RD_B23(0);
        QUAD(0, 2);
        BARRIER();
        // R2(e): ar47 -> QUAD(4,2),QUAD(4,0); stage B-half(e+2)->lB0 [WAR:
        // tile e's br reads ended at R1's barrier]; VMW(4) retires tile o
        RD_A47(0);
        STAGEQ_(0, e + 2, 2); STAGEQ_(0, e + 2, 3);
        QUAD(4, 2); QUAD(4, 0);
        VMW(4); BARRIER();                 // publishes tile o
        // R3(o): stage A-half(e+2)->lA0 [WAR: tile e's ar47 ended at R2's
        // barrier]; reads buf1
        RD_A03_B01(1);
        STAGEQ_(0, e + 2, 0); STAGEQ_(0, e + 2, 1);
        QUAD(0, 0);
        RD_B23(1);
        QUAD(0, 2);
        BARRIER();
        // R4(o): ar47 -> QUADs; stage B-half(o+2)->lB1 [WAR: tile o's br
        // reads ended at R3's barrier]; VMW(4) retires tile e+2
        RD_A47(1);
        STAGEQ_(1, o + 2, 2); STAGEQ_(1, o + 2, 3);
        QUAD(4, 2); QUAD(4, 0);
        VMW(4); BARRIER();                 // publishes tile e+2
    }

    // tail: tiles 30 (buf0), 31 (buf1). Entering: B-half(31) outstanding (4).
    RD_A03_B01(0);
    STAGEQ_(1, 31, 0); STAGEQ_(1, 31, 1);  // A-half(31)
    QUAD(0, 0);
    RD_B23(0);
    QUAD(0, 2);
    BARRIER();
    RD_A47(0);
    QUAD(4, 2); QUAD(4, 0);
    VMW(0); BARRIER();                      // publishes tile 31
    RD_A03_B01(1);
    QUAD(0, 0);
    RD_B23(1);
    QUAD(0, 2);
    RD_A47(1);
    QUAD(4, 2); QUAD(4, 0);

    // epilogue: C/D layout col = lane&15, row = (lane>>4)*4 + jj
    // out = sx[row]*sw[col]*acc + bias[col]
#pragma unroll
    for (int n = 0; n < 4; ++n) {
        int gcol = colBase + wn * 64 + n * 16 + frow;
        float swv = sw[gcol];
        float bv = bias[gcol];
#pragma unroll
        for (int m = 0; m < 8; ++m) {
            int grow0 = rowBase + wm * 128 + m * 16 + g * 4;
            float4 sx4 = *(const float4*)&sx[grow0];
            out[(size_t)(grow0 + 0) * OUT_F + gcol] = (float)acc[m][n][0] * sx4.x * swv + bv;
            out[(size_t)(grow0 + 1) * OUT_F + gcol] = (float)acc[m][n][1] * sx4.y * swv + bv;
            out[(size_t)(grow0 + 2) * OUT_F + gcol] = (float)acc[m][n][2] * sx4.z * swv + bv;
            out[(size_t)(grow0 + 3) * OUT_F + gcol] = (float)acc[m][n][3] * sx4.w * swv + bv;
        }
    }
}

// ---------- launch ----------
extern "C" void kernel_launch(void* const* d_in, const int* in_sizes, int n_in,
                              void* d_out, int out_size, void* d_ws, size_t ws_size,
                              hipStream_t stream) {
    const float* x         = (const float*)d_in[0];
    const int*   codes     = (const int*)d_in[1];
    const float* codebooks = (const float*)d_in[2];
    const float* scales    = (const float*)d_in[3];
    const float* bias      = (const float*)d_in[4];
    float* out = (float*)d_out;

    // workspace: Wq i8 [OUT_F][IN_F]; Xq i8 [M_TOK][IN_F]; sx; sw (~78.7 MB)
    signed char* Wq = (signed char*)d_ws;
    signed char* Xq = Wq + (size_t)OUT_F * IN_F;
    float* sx = (float*)(Xq + (size_t)M_TOK * IN_F);
    float* sw = sx + M_TOK;

    k_qx<<<M_TOK, 256, 0, stream>>>(x, Xq, sx);
    k_qw<<<OUT_F, 256, 0, stream>>>(codes, codebooks, scales, Wq, sw);
    // grid: (8192/256) * (11008/256) = 32 * 43 = 1376 blocks, 512 threads
    k_gemm<<<1376, 512, 0, stream>>>(Xq, Wq, sx, sw, bias, out);
}

// Round 17
// 469.562 us; speedup vs baseline: 5.4645x; 1.0027x over previous
//
#include <hip/hip_runtime.h>
#include <hip/hip_bf16.h>
#include <stdint.h>

// Problem constants (QuantizedLinear_15985868276124)
#define IN_F   4096                 // bytes per i8 row == elements
#define OUT_F  11008
#define M_TOK  8192

typedef __attribute__((ext_vector_type(4))) int   int32x4;

// ---------- block row-max reduction helper ----------
__device__ __forceinline__ float block_rowmax(float m, float* red, int t) {
    red[t] = m; __syncthreads();
    for (int s = 128; s > 0; s >>= 1) {
        if (t < s) red[t] = fmaxf(red[t], red[t + s]);
        __syncthreads();
    }
    float r = red[0]; __syncthreads();
    return fmaxf(r, 1e-8f);
}

// ---------- kernel 1: quantize x rows -> i8 + sx ----------
__global__ __launch_bounds__(256) void k_qx(
        const float* __restrict__ x, signed char* __restrict__ Xq,
        float* __restrict__ sx) {
    __shared__ float red[256];
    int r = blockIdx.x, t = threadIdx.x;
    const float4* xr = (const float4*)(x + (size_t)r * IN_F) + t * 4;
    float4 v0 = xr[0], v1 = xr[1], v2 = xr[2], v3 = xr[3];
    float m = 0.f;
#define MX4(v) m = fmaxf(m, fmaxf(fmaxf(fabsf(v.x), fabsf(v.y)), fmaxf(fabsf(v.z), fabsf(v.w))))
    MX4(v0); MX4(v1); MX4(v2); MX4(v3);
    float rm = block_rowmax(m, red, t);
    if (t == 0) sx[r] = rm / 127.f;
    float inv = 127.f / rm;
    union { signed char c[16]; uint4 u; } pk;
#define Q4(v, o) pk.c[o] = (signed char)__float2int_rn(v.x * inv);            \
                 pk.c[o+1] = (signed char)__float2int_rn(v.y * inv);          \
                 pk.c[o+2] = (signed char)__float2int_rn(v.z * inv);          \
                 pk.c[o+3] = (signed char)__float2int_rn(v.w * inv)
    Q4(v0, 0); Q4(v1, 4); Q4(v2, 8); Q4(v3, 12);
    *(uint4*)(Xq + (size_t)r * IN_F + t * 16) = pk.u;
}

// ---------- kernel 2: dequant + quantize W rows -> i8 + sw ----------
__global__ __launch_bounds__(256) void k_qw(
        const int* __restrict__ codes,
        const float* __restrict__ codebooks,
        const float* __restrict__ scales,
        signed char* __restrict__ Wq, float* __restrict__ sw) {
    __shared__ float cb[4096];  // [2][256][8]
    __shared__ float red[256];
    int o = blockIdx.x, t = threadIdx.x;
    {
        const float4* cbg = (const float4*)codebooks;
        float4* cbl = (float4*)cb;
#pragma unroll
        for (int i = 0; i < 4; ++i) cbl[t + i * 256] = cbg[t + i * 256];
    }
    __syncthreads();
    const int2* cp = (const int2*)codes + (size_t)o * 512 + t * 2;
    int2 c0 = cp[0], c1 = cp[1];
    float e[16]; float m = 0.f;
#pragma unroll
    for (int j = 0; j < 8; ++j) {
        e[j]     = cb[c0.x * 8 + j] + cb[2048 + c0.y * 8 + j];
        e[8 + j] = cb[c1.x * 8 + j] + cb[2048 + c1.y * 8 + j];
    }
#pragma unroll
    for (int j = 0; j < 16; ++j) m = fmaxf(m, fabsf(e[j]));
    float rm = block_rowmax(m, red, t);
    if (t == 0) sw[o] = scales[o] * rm / 127.f;
    float inv = 127.f / rm;
    union { signed char c[16]; uint4 u; } pk;
#pragma unroll
    for (int j = 0; j < 16; ++j) pk.c[j] = (signed char)__float2int_rn(e[j] * inv);
    *(uint4*)(Wq + (size_t)o * IN_F + t * 16) = pk.u;
}

// ---------- kernel 3: 256x256 i8 GEMM, QUAD-FIRST read-ahead regions -------
// R17: every region = {QUAD(operands read >=1 region earlier); reads(next);
// stage; [VMW]; barrier}. The lgkm wait before each QUAD targets OLD reads
// (drained during the previous QUAD/barrier) -> near-zero stall; this
// region's reads drain under the next region's QUAD -> LDS || MFMA overlap.
// Single ar[] works: a read overwriting ar issues AFTER the QUAD consuming
// the old ar (register dep handled by compiler) -> no VGPR blowup (R15
// lesson: acc=128 AGPR + ~128 VGPR must stay <= 256/thread).
// Region table (pair t=even buf0, t+1 buf1):
//  R1: QD(t-1)      ; rd ar03(t),br01(t) ; stage (t+1)A          ; bar
//  R2: QA(t)=ar*brA ; rd br23(t)                                  ; bar
//  R3: QB(t)=ar*brB ; rd ar47(t)                                  ; bar
//  R4: QC(t)=ar*brB ; stage (t+2)B ; VMW(4)                       ; bar  [pub t+1]
//  R5: QD(t)=ar*brA ; rd ar03(t+1),br01(t+1) ; stage (t+2)A       ; bar
//  R6: QA(t+1)      ; rd br23(t+1)                                ; bar
//  R7: QB(t+1)      ; rd ar47(t+1)                                ; bar
//  R8: QC(t+1)      ; stage (t+3)B ; VMW(4)                       ; bar  [pub t+2]
// WAR: every stage is >=2 regions after its target rows' reads issued
// (consumed by the intervening QUAD across all waves before the barrier).
// Ledger @R4: outstanding {t+1B@prevR8, t+1A@R1, t+2B@R4} = 12 -> VMW(4)
// retires t+1 exactly; @R8 symmetric for t+2.

#define BARRIER() __builtin_amdgcn_s_barrier()
#define VMW(n)    asm volatile("s_waitcnt vmcnt(" #n ")")

#define GL16(gp, lp) __builtin_amdgcn_global_load_lds(                        \
    (const __attribute__((address_space(1))) void*)(gp),                      \
    (__attribute__((address_space(3))) void*)(lp), 16, 0, 0)

__global__ __launch_bounds__(512, 2) void k_gemm(
        const signed char* __restrict__ A,   // [M_TOK][IN_F] i8
        const signed char* __restrict__ B,   // [OUT_F][IN_F] i8 (B^T layout)
        const float* __restrict__ sx,        // [M_TOK]
        const float* __restrict__ sw,        // [OUT_F]
        const float* __restrict__ bias,
        float* __restrict__ out) {
    __shared__ signed char lA0[256 * 128];   // 32 KiB each
    __shared__ signed char lA1[256 * 128];
    __shared__ signed char lB0[256 * 128];
    __shared__ signed char lB1[256 * 128];

    const int tid = threadIdx.x;
    const int l = tid & 63;
    const int w = tid >> 6;            // wave 0..7
    const int wm = w >> 2, wn = w & 3; // 2 x 4 wave grid; wave tile 128x64

    // T1: bijective XCD swizzle. grid 1376 = 8 XCD * (4 row-chunks * 43 cols)
    int lid = blockIdx.x;
    int xcd = lid & 7, j = lid >> 3;
    int bx = j >> 2;                   // col block 0..42
    int by = (xcd << 2) + (j & 3);     // row block 0..31
    const int rowBase = by * 256;
    const int colBase = bx * 256;

    // ---- staging addressing (swizzle on GLOBAL source; LDS linear)
    const int srow = w * 8 + (l >> 3);
    const int scol = ((l & 7) ^ ((l >> 3) & 7)) << 4;   // byte offset in row
    const signed char* gA = A + (size_t)(rowBase + srow) * IN_F + scol;
    const signed char* gB = B + (size_t)(colBase + srow) * IN_F + scol;
    signed char* lA0w = &lA0[w * 8 * 128];
    signed char* lA1w = &lA1[w * 8 * 128];
    signed char* lB0w = &lB0[w * 8 * 128];
    signed char* lB1w = &lB1[w * 8 * 128];

    // stage half of K-tile t into buffer P: H=0 -> A rows 0-255 (q0,q1),
    // H=1 -> B rows (q2,q3). 4 GL16 each.
#define STAGEH_(P, t, H) do {                                                 \
    const signed char* _g = ((H) ? gB : gA) + (size_t)(t) * 128;              \
    signed char* _l = ((H) ? lB##P##w : lA##P##w);                            \
    GL16(_g,                       _l);                                       \
    GL16(_g +  64 * IN_F,          _l +  64 * 128);                           \
    GL16(_g + 128 * IN_F,          _l + 128 * 128);                           \
    GL16(_g + 192 * IN_F,          _l + 192 * 128);                           \
} while (0)

    // ---- fragment reads
    const int frow = l & 15, g = l >> 4;
    const int cho0 = ((g ^ (frow & 7)) << 4);
    const int cho1 = (((4 + g) ^ (frow & 7)) << 4);
    const char* rowA0 = (const char*)&lA0[(wm * 128 + frow) * 128];
    const char* rowA1 = (const char*)&lA1[(wm * 128 + frow) * 128];
    const char* rowB0 = (const char*)&lB0[(wn * 64 + frow) * 128];
    const char* rowB1 = (const char*)&lB1[(wn * 64 + frow) * 128];
#define LDA_(P, m, kk) (*(const int32x4*)(rowA##P + (m) * 2048 + ((kk) ? cho1 : cho0)))
#define LDB_(P, n, kk) (*(const int32x4*)(rowB##P + (n) * 2048 + ((kk) ? cho1 : cho0)))

    int32x4 acc[8][4] = {};
    int32x4 ar[4][2];    // ar03 OR ar47 of the current tile (time-shared)
    int32x4 brA[2][2];   // br01 of current tile
    int32x4 brB[2][2];   // br23 of current tile

#define QUADQ(M0, N0, BR) do {                                                \
    __builtin_amdgcn_s_setprio(1);                                            \
    _Pragma("unroll") for (int mm = 0; mm < 4; ++mm)                          \
    _Pragma("unroll") for (int nn = 0; nn < 2; ++nn)                          \
    _Pragma("unroll") for (int kk = 0; kk < 2; ++kk)                          \
        acc[(M0) + mm][(N0) + nn] = __builtin_amdgcn_mfma_i32_16x16x64_i8(    \
            ar[mm][kk], BR[nn][kk], acc[(M0) + mm][(N0) + nn], 0, 0, 0);      \
    __builtin_amdgcn_s_setprio(0);                                            \
} while (0)

#define RD_AR03(P) do {                                                       \
    _Pragma("unroll") for (int mm = 0; mm < 4; ++mm) {                        \
        ar[mm][0] = LDA_(P, mm, 0); ar[mm][1] = LDA_(P, mm, 1); }             \
} while (0)
#define RD_AR47(P) do {                                                       \
    _Pragma("unroll") for (int mm = 0; mm < 4; ++mm) {                        \
        ar[mm][0] = LDA_(P, 4 + mm, 0); ar[mm][1] = LDA_(P, 4 + mm, 1); }     \
} while (0)
#define RD_BR01(P) do {                                                       \
    brA[0][0] = LDB_(P, 0, 0); brA[0][1] = LDB_(P, 0, 1);                     \
    brA[1][0] = LDB_(P, 1, 0); brA[1][1] = LDB_(P, 1, 1);                     \
} while (0)
#define RD_BR23(P) do {                                                       \
    brB[0][0] = LDB_(P, 2, 0); brB[0][1] = LDB_(P, 2, 1);                     \
    brB[1][0] = LDB_(P, 3, 0); brB[1][1] = LDB_(P, 3, 1);                     \
} while (0)

    // prologue: stage t0 full (buf0) + t1 B-half (buf1); VMW(4) retires t0;
    // barrier publishes t0. Then R1(0) without QD: reads + stage t1 A-half.
    STAGEH_(0, 0, 0); STAGEH_(0, 0, 1);
    STAGEH_(1, 1, 1);
    VMW(4); BARRIER();
    RD_AR03(0); RD_BR01(0);
    STAGEH_(1, 1, 0);
    BARRIER();

    // main loop: 15 iterations, pairs (t,t+1) = (0,1)..(28,29).
    // Body = R2..R8 + R1next (QD(t+1), reads for t+2, stage (t+3)A).
    for (int i = 0; i < 15; ++i) {
        int t = 2 * i;
        // R2: QA(t); rd br23(t)
        QUADQ(0, 0, brA);
        RD_BR23(0);
        BARRIER();
        // R3: QB(t); rd ar47(t)  [read overwrites ar AFTER QB consumes ar03]
        QUADQ(0, 2, brB);
        RD_AR47(0);
        BARRIER();
        // R4: QC(t); stage (t+2)B -> lB0; VMW(4) retires t+1; bar publishes t+1
        QUADQ(4, 2, brB);
        STAGEH_(0, t + 2, 1);
        VMW(4); BARRIER();
        // R5: QD(t); rd ar03(t+1)+br01(t+1); stage (t+2)A -> lA0
        QUADQ(4, 0, brA);
        RD_AR03(1); RD_BR01(1);
        STAGEH_(0, t + 2, 0);
        BARRIER();
        // R6: QA(t+1); rd br23(t+1)
        QUADQ(0, 0, brA);
        RD_BR23(1);
        BARRIER();
        // R7: QB(t+1); rd ar47(t+1)
        QUADQ(0, 2, brB);
        RD_AR47(1);
        BARRIER();
        // R8: QC(t+1); stage (t+3)B -> lB1; VMW(4) retires t+2; bar publishes
        QUADQ(4, 2, brB);
        STAGEH_(1, t + 3, 1);
        VMW(4); BARRIER();
        // R1next: QD(t+1); rd ar03(t+2)+br01(t+2); stage (t+3)A -> lA1
        QUADQ(4, 0, brA);
        RD_AR03(0); RD_BR01(0);
        STAGEH_(1, t + 3, 0);
        BARRIER();
    }

    // tail: pair (30,31). Entering: ar=ar03(30), brA=br01(30);
    // outstanding loads = 31B(4) + 31A(4).
    QUADQ(0, 0, brA);            // QA(30)
    RD_BR23(0);
    BARRIER();
    QUADQ(0, 2, brB);            // QB(30)
    RD_AR47(0);
    BARRIER();
    QUADQ(4, 2, brB);            // QC(30)
    VMW(0); BARRIER();           // retires + publishes tile 31
    QUADQ(4, 0, brA);            // QD(30)
    RD_AR03(1); RD_BR01(1);
    BARRIER();
    QUADQ(0, 0, brA);            // QA(31)
    RD_BR23(1);
    BARRIER();
    QUADQ(0, 2, brB);            // QB(31)
    RD_AR47(1);
    BARRIER();
    QUADQ(4, 2, brB);            // QC(31)
    QUADQ(4, 0, brA);            // QD(31)

    // epilogue: C/D layout col = lane&15, row = (lane>>4)*4 + jj
    // out = sx[row]*sw[col]*acc + bias[col]
#pragma unroll
    for (int n = 0; n < 4; ++n) {
        int gcol = colBase + wn * 64 + n * 16 + frow;
        float swv = sw[gcol];
        float bv = bias[gcol];
#pragma unroll
        for (int m = 0; m < 8; ++m) {
            int grow0 = rowBase + wm * 128 + m * 16 + g * 4;
            float4 sx4 = *(const float4*)&sx[grow0];
            out[(size_t)(grow0 + 0) * OUT_F + gcol] = (float)acc[m][n][0] * sx4.x * swv + bv;
            out[(size_t)(grow0 + 1) * OUT_F + gcol] = (float)acc[m][n][1] * sx4.y * swv + bv;
            out[(size_t)(grow0 + 2) * OUT_F + gcol] = (float)acc[m][n][2] * sx4.z * swv + bv;
            out[(size_t)(grow0 + 3) * OUT_F + gcol] = (float)acc[m][n][3] * sx4.w * swv + bv;
        }
    }
}

// ---------- launch ----------
extern "C" void kernel_launch(void* const* d_in, const int* in_sizes, int n_in,
                              void* d_out, int out_size, void* d_ws, size_t ws_size,
                              hipStream_t stream) {
    const float* x         = (const float*)d_in[0];
    const int*   codes     = (const int*)d_in[1];
    const float* codebooks = (const float*)d_in[2];
    const float* scales    = (const float*)d_in[3];
    const float* bias      = (const float*)d_in[4];
    float* out = (float*)d_out;

    // workspace: Wq i8 [OUT_F][IN_F]; Xq i8 [M_TOK][IN_F]; sx; sw (~78.7 MB)
    signed char* Wq = (signed char*)d_ws;
    signed char* Xq = Wq + (size_t)OUT_F * IN_F;
    float* sx = (float*)(Xq + (size_t)M_TOK * IN_F);
    float* sw = sx + M_TOK;

    k_qx<<<M_TOK, 256, 0, stream>>>(x, Xq, sx);
    k_qw<<<OUT_F, 256, 0, stream>>>(codes, codebooks, scales, Wq, sw);
    // grid: (8192/256) * (11008/256) = 32 * 43 = 1376 blocks, 512 threads
    k_gemm<<<1376, 512, 0, stream>>>(Xq, Wq, sx, sw, bias, out);
}

// Round 18
// 458.103 us; speedup vs baseline: 5.6012x; 1.0250x over previous
//
#include <hip/hip_runtime.h>
#include <hip/hip_bf16.h>
#include <stdint.h>

// Problem constants (QuantizedLinear_15985868276124)
#define IN_F   4096                 // bytes per i8 row == elements
#define OUT_F  11008
#define M_TOK  8192

typedef __attribute__((ext_vector_type(4))) int   int32x4;

// ---------- kernel 1: merged prep — quantize x rows AND W rows ----------
// blocks [0, M_TOK): x row -> Xq,sx ; blocks [M_TOK, M_TOK+OUT_F): W row -> Wq,sw
__global__ __launch_bounds__(256) void k_prep(
        const float* __restrict__ x,
        const int* __restrict__ codes,
        const float* __restrict__ codebooks,
        const float* __restrict__ scales,
        signed char* __restrict__ Xq, float* __restrict__ sx,
        signed char* __restrict__ Wq, float* __restrict__ sw) {
    __shared__ float cb[4096];  // qw branch only
    __shared__ float red[256];
    int t = threadIdx.x;

    if (blockIdx.x < M_TOK) {
        // ---- quantize x row ----
        int r = blockIdx.x;
        const float4* xr = (const float4*)(x + (size_t)r * IN_F) + t * 4;
        float4 v0 = xr[0], v1 = xr[1], v2 = xr[2], v3 = xr[3];
        float m = 0.f;
#define MX4(v) m = fmaxf(m, fmaxf(fmaxf(fabsf(v.x), fabsf(v.y)), fmaxf(fabsf(v.z), fabsf(v.w))))
        MX4(v0); MX4(v1); MX4(v2); MX4(v3);
        red[t] = m; __syncthreads();
        for (int s = 128; s > 0; s >>= 1) {
            if (t < s) red[t] = fmaxf(red[t], red[t + s]);
            __syncthreads();
        }
        float rm = fmaxf(red[0], 1e-8f);
        if (t == 0) sx[r] = rm / 127.f;
        float inv = 127.f / rm;
        union { signed char c[16]; uint4 u; } pk;
#define Q4(v, o) pk.c[o] = (signed char)__float2int_rn(v.x * inv);            \
                 pk.c[o+1] = (signed char)__float2int_rn(v.y * inv);          \
                 pk.c[o+2] = (signed char)__float2int_rn(v.z * inv);          \
                 pk.c[o+3] = (signed char)__float2int_rn(v.w * inv)
        Q4(v0, 0); Q4(v1, 4); Q4(v2, 8); Q4(v3, 12);
        *(uint4*)(Xq + (size_t)r * IN_F + t * 16) = pk.u;
    } else {
        // ---- dequant + quantize W row ----
        int o = blockIdx.x - M_TOK;
        {
            const float4* cbg = (const float4*)codebooks;
            float4* cbl = (float4*)cb;
#pragma unroll
            for (int i = 0; i < 4; ++i) cbl[t + i * 256] = cbg[t + i * 256];
        }
        __syncthreads();
        const int2* cp = (const int2*)codes + (size_t)o * 512 + t * 2;
        int2 c0 = cp[0], c1 = cp[1];
        float e[16]; float m = 0.f;
#pragma unroll
        for (int j = 0; j < 8; ++j) {
            e[j]     = cb[c0.x * 8 + j] + cb[2048 + c0.y * 8 + j];
            e[8 + j] = cb[c1.x * 8 + j] + cb[2048 + c1.y * 8 + j];
        }
#pragma unroll
        for (int j = 0; j < 16; ++j) m = fmaxf(m, fabsf(e[j]));
        red[t] = m; __syncthreads();
        for (int s = 128; s > 0; s >>= 1) {
            if (t < s) red[t] = fmaxf(red[t], red[t + s]);
            __syncthreads();
        }
        float rm = fmaxf(red[0], 1e-8f);
        if (t == 0) sw[o] = scales[o] * rm / 127.f;
        float inv = 127.f / rm;
        union { signed char c[16]; uint4 u; } pk;
#pragma unroll
        for (int j = 0; j < 16; ++j) pk.c[j] = (signed char)__float2int_rn(e[j] * inv);
        *(uint4*)(Wq + (size_t)o * IN_F + t * 16) = pk.u;
    }
}

// ---------- kernel 2: 256x256 i8 GEMM (R14 structure, NO setprio) ----------
// R18: exact R14 (best known, 400us) minus s_setprio around QUADs.
// Theory: setprio(1) during a wave's MFMA cluster starves the co-resident
// wave's ds_read ISSUE (prio-0 loses every arbitration) -> LDS pipe idle
// during MFMA windows -> LDS(2304)+MFMA(2611) serialize to the measured
// ~5580 cyc/K-tile in ALL R4-R17 schedules. Equal priority lets the SIMD
// scheduler interleave reads into MFMA-stall slots (m114 cross-wave overlap).

#define BARRIER() __builtin_amdgcn_s_barrier()
#define VMW(n)    asm volatile("s_waitcnt vmcnt(" #n ")")

#define GL16(gp, lp) __builtin_amdgcn_global_load_lds(                        \
    (const __attribute__((address_space(1))) void*)(gp),                      \
    (__attribute__((address_space(3))) void*)(lp), 16, 0, 0)

__global__ __launch_bounds__(512, 2) void k_gemm(
        const signed char* __restrict__ A,   // [M_TOK][IN_F] i8
        const signed char* __restrict__ B,   // [OUT_F][IN_F] i8 (B^T layout)
        const float* __restrict__ sx,        // [M_TOK]
        const float* __restrict__ sw,        // [OUT_F]
        const float* __restrict__ bias,
        float* __restrict__ out) {
    __shared__ signed char lA0[256 * 128];   // 32 KiB each
    __shared__ signed char lA1[256 * 128];
    __shared__ signed char lB0[256 * 128];
    __shared__ signed char lB1[256 * 128];

    const int tid = threadIdx.x;
    const int l = tid & 63;
    const int w = tid >> 6;            // wave 0..7
    const int wm = w >> 2, wn = w & 3; // 2 x 4 wave grid; wave tile 128x64

    // T1: bijective XCD swizzle. grid 1376 = 8 XCD * (4 row-chunks * 43 cols)
    int lid = blockIdx.x;
    int xcd = lid & 7, j = lid >> 3;
    int bx = j >> 2;                   // col block 0..42
    int by = (xcd << 2) + (j & 3);     // row block 0..31
    const int rowBase = by * 256;
    const int colBase = bx * 256;

    // ---- staging addressing (swizzle on GLOBAL source; LDS linear)
    const int srow = w * 8 + (l >> 3);
    const int scol = ((l & 7) ^ ((l >> 3) & 7)) << 4;   // byte offset in row
    const signed char* gA = A + (size_t)(rowBase + srow) * IN_F + scol;
    const signed char* gB = B + (size_t)(colBase + srow) * IN_F + scol;
    signed char* lA0w = &lA0[w * 8 * 128];
    signed char* lA1w = &lA1[w * 8 * 128];
    signed char* lB0w = &lB0[w * 8 * 128];
    signed char* lB1w = &lB1[w * 8 * 128];

#define STAGEQ_(P, t, q) do {                                                 \
    const signed char* _g = (((q) < 2) ? gA : gB) + (size_t)(t) * 128;        \
    signed char* _l = (((q) < 2) ? lA##P##w : lB##P##w);                      \
    const int _r = ((q) & 1) * 128;                                           \
    GL16(_g + (size_t)_r * IN_F,        _l + _r * 128);                       \
    GL16(_g + (size_t)(_r + 64) * IN_F, _l + (_r + 64) * 128);                \
} while (0)

    // ---- fragment reads
    const int frow = l & 15, g = l >> 4;
    const int cho0 = ((g ^ (frow & 7)) << 4);
    const int cho1 = (((4 + g) ^ (frow & 7)) << 4);
    const char* rowA0 = (const char*)&lA0[(wm * 128 + frow) * 128];
    const char* rowA1 = (const char*)&lA1[(wm * 128 + frow) * 128];
    const char* rowB0 = (const char*)&lB0[(wn * 64 + frow) * 128];
    const char* rowB1 = (const char*)&lB1[(wn * 64 + frow) * 128];
#define LDA_(P, m, kk) (*(const int32x4*)(rowA##P + (m) * 2048 + ((kk) ? cho1 : cho0)))
#define LDB_(P, n, kk) (*(const int32x4*)(rowB##P + (n) * 2048 + ((kk) ? cho1 : cho0)))

    int32x4 acc[8][4] = {};
    int32x4 ar[4][2], br[4][2];

    // NO setprio — equal wave priority so ds_read issue interleaves with MFMA
#define QUAD(M0, N0) do {                                                     \
    _Pragma("unroll") for (int mm = 0; mm < 4; ++mm)                          \
    _Pragma("unroll") for (int nn = 0; nn < 2; ++nn)                          \
    _Pragma("unroll") for (int kk = 0; kk < 2; ++kk)                          \
        acc[(M0) + mm][(N0) + nn] = __builtin_amdgcn_mfma_i32_16x16x64_i8(    \
            ar[mm][kk], br[(N0) + nn][kk], acc[(M0) + mm][(N0) + nn], 0, 0, 0);\
} while (0)

#define RD_A03_B01(P) do {                                                    \
    _Pragma("unroll") for (int mm = 0; mm < 4; ++mm) {                        \
        ar[mm][0] = LDA_(P, mm, 0); ar[mm][1] = LDA_(P, mm, 1); }             \
    br[0][0] = LDB_(P, 0, 0); br[0][1] = LDB_(P, 0, 1);                       \
    br[1][0] = LDB_(P, 1, 0); br[1][1] = LDB_(P, 1, 1);                       \
} while (0)
#define RD_B23(P) do {                                                        \
    br[2][0] = LDB_(P, 2, 0); br[2][1] = LDB_(P, 2, 1);                       \
    br[3][0] = LDB_(P, 3, 0); br[3][1] = LDB_(P, 3, 1);                       \
} while (0)
#define RD_A47(P) do {                                                        \
    _Pragma("unroll") for (int mm = 0; mm < 4; ++mm) {                        \
        ar[mm][0] = LDA_(P, 4 + mm, 0); ar[mm][1] = LDA_(P, 4 + mm, 1); }     \
} while (0)

    // prologue: stage tile0 (buf0) + tile1 (buf1, C/D order); VMW(8) -> t0 in
    STAGEQ_(0, 0, 0); STAGEQ_(0, 0, 1); STAGEQ_(0, 0, 2); STAGEQ_(0, 0, 3);
    STAGEQ_(1, 1, 2); STAGEQ_(1, 1, 3); STAGEQ_(1, 1, 0); STAGEQ_(1, 1, 1);
    VMW(8); BARRIER();

    // main loop: 2 K-tiles/iter (t=2i buf0, t+1 buf1); i=0..14 (tiles 0..31)
    for (int i = 0; i < 15; ++i) {
        int t = 2 * i;
        // A0
        RD_A03_B01(0);
        QUAD(0, 0); BARRIER();
        // B0
        RD_B23(0);
        QUAD(0, 2); BARRIER();
        // C0: stage B-half of t+2 -> buf0
        RD_A47(0); STAGEQ_(0, t + 2, 2); STAGEQ_(0, t + 2, 3);
        QUAD(4, 2); BARRIER();
        // D0: stage A-half of t+2; VMW(8) retires t+1; barrier publishes it
        STAGEQ_(0, t + 2, 0); STAGEQ_(0, t + 2, 1); VMW(8);
        QUAD(4, 0); BARRIER();
        // A1
        RD_A03_B01(1);
        QUAD(0, 0); BARRIER();
        // B1
        RD_B23(1);
        QUAD(0, 2); BARRIER();
        // C1: stage B-half of t+3 -> buf1
        RD_A47(1); STAGEQ_(1, t + 3, 2); STAGEQ_(1, t + 3, 3);
        QUAD(4, 2); BARRIER();
        // D1: stage A-half of t+3; VMW(8) retires t+2; barrier publishes it
        STAGEQ_(1, t + 3, 0); STAGEQ_(1, t + 3, 1); VMW(8);
        QUAD(4, 0); BARRIER();
    }

    // peeled last pair (tiles 30 buf0, 31 buf1); no new staging
    RD_A03_B01(0);
    QUAD(0, 0); BARRIER();
    RD_B23(0);
    QUAD(0, 2); BARRIER();
    RD_A47(0);
    QUAD(4, 2); BARRIER();
    VMW(0);                                  // tile 31 complete; publish
    QUAD(4, 0); BARRIER();
    RD_A03_B01(1);
    QUAD(0, 0); BARRIER();
    RD_B23(1);
    QUAD(0, 2); BARRIER();
    RD_A47(1);
    QUAD(4, 2); BARRIER();
    QUAD(4, 0);

    // epilogue: C/D layout col = lane&15, row = (lane>>4)*4 + jj
    // out = sx[row]*sw[col]*acc + bias[col]
#pragma unroll
    for (int n = 0; n < 4; ++n) {
        int gcol = colBase + wn * 64 + n * 16 + frow;
        float swv = sw[gcol];
        float bv = bias[gcol];
#pragma unroll
        for (int m = 0; m < 8; ++m) {
            int grow0 = rowBase + wm * 128 + m * 16 + g * 4;
            float4 sx4 = *(const float4*)&sx[grow0];
            out[(size_t)(grow0 + 0) * OUT_F + gcol] = (float)acc[m][n][0] * sx4.x * swv + bv;
            out[(size_t)(grow0 + 1) * OUT_F + gcol] = (float)acc[m][n][1] * sx4.y * swv + bv;
            out[(size_t)(grow0 + 2) * OUT_F + gcol] = (float)acc[m][n][2] * sx4.z * swv + bv;
            out[(size_t)(grow0 + 3) * OUT_F + gcol] = (float)acc[m][n][3] * sx4.w * swv + bv;
        }
    }
}

// ---------- launch ----------
extern "C" void kernel_launch(void* const* d_in, const int* in_sizes, int n_in,
                              void* d_out, int out_size, void* d_ws, size_t ws_size,
                              hipStream_t stream) {
    const float* x         = (const float*)d_in[0];
    const int*   codes     = (const int*)d_in[1];
    const float* codebooks = (const float*)d_in[2];
    const float* scales    = (const float*)d_in[3];
    const float* bias      = (const float*)d_in[4];
    float* out = (float*)d_out;

    // workspace: Wq i8 [OUT_F][IN_F]; Xq i8 [M_TOK][IN_F]; sx; sw (~78.7 MB)
    signed char* Wq = (signed char*)d_ws;
    signed char* Xq = Wq + (size_t)OUT_F * IN_F;
    float* sx = (float*)(Xq + (size_t)M_TOK * IN_F);
    float* sw = sx + M_TOK;

    k_prep<<<M_TOK + OUT_F, 256, 0, stream>>>(x, codes, codebooks, scales,
                                              Xq, sx, Wq, sw);
    // grid: (8192/256) * (11008/256) = 32 * 43 = 1376 blocks, 512 threads
    k_gemm<<<1376, 512, 0, stream>>>(Xq, Wq, sx, sw, bias, out);
}